// Round 19
// baseline (142.919 us; speedup 1.0000x reference)
//
#include <hip/hip_runtime.h>
#include <hip/hip_bf16.h>
#include <stdint.h>

typedef __attribute__((ext_vector_type(4)))  float  f32x4;
typedef __attribute__((ext_vector_type(16))) float  f32x16;
typedef __attribute__((ext_vector_type(8)))  short  bf8;   // 8 bf16 bit patterns (4 VGPRs)
typedef __attribute__((ext_vector_type(4)))  short  bf4;
typedef __attribute__((ext_vector_type(4)))  float  fvec4;
typedef __attribute__((ext_vector_type(4)))  unsigned uvec4;
typedef __attribute__((ext_vector_type(2)))  unsigned uvec2;

#define AS1 __attribute__((address_space(1)))
#define AS3 __attribute__((address_space(3)))

#if __has_builtin(__builtin_amdgcn_exp2f)
#define EXP2(x) __builtin_amdgcn_exp2f(x)
#else
#define EXP2(x) exp2f(x)
#endif

__device__ __forceinline__ short sbf(float f) {
  __hip_bfloat16 h = __float2bfloat16(f);
  return *reinterpret_cast<short*>(&h);
}

// packed f32x2 -> bf16x2 in one HW instruction (low = lo, high = hi)
__device__ __forceinline__ unsigned pk2(float lo, float hi) {
  unsigned r;
  asm("v_cvt_pk_bf16_f32 %0, %1, %2" : "=v"(r) : "v"(lo), "v"(hi));
  return r;
}

// ---------------- all 4 weight transposes in ONE launch ----------------
__device__ __forceinline__ void tr_tile(const float* __restrict__ src,
                                        short* __restrict__ dst, int K,
                                        float scale, int kx, int ny) {
  __shared__ short t[64][65];
  const int k0 = kx * 64, n0 = ny * 64;
  const int tx = threadIdx.x & 15, ty = threadIdx.x >> 4;   // 16x16
  #pragma unroll
  for (int i = 0; i < 4; ++i) {
    int k = ty + i * 16;
    fvec4 v = *(const fvec4*)(src + (size_t)(k0 + k) * 512 + n0 + tx * 4);
    t[tx * 4 + 0][k] = sbf(v[0] * scale);
    t[tx * 4 + 1][k] = sbf(v[1] * scale);
    t[tx * 4 + 2][k] = sbf(v[2] * scale);
    t[tx * 4 + 3][k] = sbf(v[3] * scale);
  }
  __syncthreads();
  #pragma unroll
  for (int i = 0; i < 4; ++i) {
    int n = ty + i * 16;
    bf4 o = *(bf4*)&t[n][tx * 4];
    *(bf4*)(dst + (size_t)(n0 + n) * K + k0 + tx * 4) = o;
  }
}

__global__ __launch_bounds__(256)
void prep_weights(const float* __restrict__ wq, const float* __restrict__ wk,
                  const float* __restrict__ wv, const float* __restrict__ wo,
                  short* __restrict__ wqT, short* __restrict__ wkvT,
                  short* __restrict__ woT, float qscale) {
  int bx = blockIdx.x;
  if (bx < 64)        tr_tile(wq, wqT, 512, qscale, bx & 7, bx >> 3);
  else if (bx < 160)  { int l = bx - 64;  tr_tile(wk, wkvT,            768, 1.0f, l % 12, l / 12); }
  else if (bx < 256)  { int l = bx - 160; tr_tile(wv, wkvT + 512*768,  768, 1.0f, l % 12, l / 12); }
  else                { int l = bx - 256; tr_tile(wo, woT, 512, 1.0f, l & 7, l >> 3); }
}

// ---------------- gemm128: 128x128 tile, 4 waves (proven R12/R16, KV-proj) ----------------
// 1-D grid with XCD grouping (256 blocks, bijective). 2-phase dbuf, vmcnt(0)/K-step.
// AF32: A fp32 reg-staged via v_cvt_pk + swizzled ds_write (same LDS image).
// EPI: 0 bf16 C; 1 f32 C + bias; 2 KV split (K->[bh][key][64]; V->[bh][d][512]).
template<int EPI, bool AF32>
__global__ __launch_bounds__(256, 3)
void gemm128(const void* __restrict__ Av, const short* __restrict__ Bt,
             void* __restrict__ Cout, void* __restrict__ Cout2,
             const float* __restrict__ bias, int M, int N, int K) {
  __shared__ short As[2][4096];
  __shared__ short Bs[2][4096];
  const short* A16 = (const short*)Av;
  const float* A32 = (const float*)Av;
  const int tid = threadIdx.x;
  const int w = tid >> 6, l = tid & 63, g = l >> 4, c15 = l & 15;
  const int nbN = N >> 7;
  const int vv = (blockIdx.x & 7) * (gridDim.x >> 3) + (blockIdx.x >> 3);
  const int mbase = (vv / nbN) * 128, nbase = (vv % nbN) * 128;
  const int wr = (w >> 1) << 6, wc = (w & 1) << 6;

  f32x4 acc[4][4];
  #pragma unroll
  for (int mi = 0; mi < 4; ++mi)
    #pragma unroll
    for (int ni = 0; ni < 4; ++ni) acc[mi][ni] = (f32x4){0.f, 0.f, 0.f, 0.f};

  int rowS[2], loS[2];
  #pragma unroll
  for (int p = 0; p < 2; ++p) {
    int pb = p * 4096 + tid * 16;
    rowS[p] = pb >> 6;
    loS[p] = ((pb & 63) ^ ((rowS[p] & 3) << 4)) >> 1;
  }

  const int ar = tid >> 1, ac0 = (tid & 1) * 16, acl = (tid & 1) * 2;
  short* wdst0 = &As[0][ar * 32 + 8 * ((acl + 0) ^ (ar & 3))];
  short* wdst1 = &As[0][ar * 32 + 8 * ((acl + 1) ^ (ar & 3))];

  auto stageB = [&](int ks, int b) {
    #pragma unroll
    for (int p = 0; p < 2; ++p) {
      const short* gb = Bt + (size_t)(nbase + rowS[p]) * K + (ks << 5) + loS[p];
      __builtin_amdgcn_global_load_lds((const AS1 void*)gb,
          (AS3 void*)(&Bs[b][p * 2048 + w * 512]), 16, 0, 0);
    }
  };
  auto stageA16 = [&](int ks, int b) {
    #pragma unroll
    for (int p = 0; p < 2; ++p) {
      const short* ga = A16 + (size_t)(mbase + rowS[p]) * K + (ks << 5) + loS[p];
      __builtin_amdgcn_global_load_lds((const AS1 void*)ga,
          (AS3 void*)(&As[b][p * 2048 + w * 512]), 16, 0, 0);
    }
  };

  const int nk = K >> 5;
  fvec4 a0, a1, a2, a3;
  auto loadA32 = [&](int ks) {
    const float* p = A32 + (size_t)(mbase + ar) * K + (ks << 5) + ac0;
    a0 = *(const fvec4*)(p);
    a1 = *(const fvec4*)(p + 4);
    a2 = *(const fvec4*)(p + 8);
    a3 = *(const fvec4*)(p + 12);
  };
  auto writeA32 = [&](int b) {
    uvec4 w0, w1;
    w0[0] = pk2(a0[0], a0[1]); w0[1] = pk2(a0[2], a0[3]);
    w0[2] = pk2(a1[0], a1[1]); w0[3] = pk2(a1[2], a1[3]);
    w1[0] = pk2(a2[0], a2[1]); w1[1] = pk2(a2[2], a2[3]);
    w1[2] = pk2(a3[0], a3[1]); w1[3] = pk2(a3[2], a3[3]);
    *(uvec4*)(wdst0 + b * 4096) = w0;
    *(uvec4*)(wdst1 + b * 4096) = w1;
  };

  if (AF32) { loadA32(0); writeA32(0); }
  else      { stageA16(0, 0); }
  stageB(0, 0);

  int buf = 0;
  for (int ks = 0; ks < nk; ++ks) {
    asm volatile("s_waitcnt vmcnt(0) lgkmcnt(0)\ns_barrier" ::: "memory");
    if (ks + 1 < nk) {
      if (AF32) loadA32(ks + 1);
      else      stageA16(ks + 1, buf ^ 1);
      stageB(ks + 1, buf ^ 1);
    }

    bf8 af[4], bfr[4];
    #pragma unroll
    for (int mi = 0; mi < 4; ++mi) {
      int row = wr + mi * 16 + c15;
      af[mi] = *(const bf8*)&As[buf][(row << 5) + ((g << 3) ^ ((row & 3) << 3))];
    }
    #pragma unroll
    for (int ni = 0; ni < 4; ++ni) {
      int row = wc + ni * 16 + c15;
      bfr[ni] = *(const bf8*)&Bs[buf][(row << 5) + ((g << 3) ^ ((row & 3) << 3))];
    }
    #pragma unroll
    for (int mi = 0; mi < 4; ++mi)
      #pragma unroll
      for (int ni = 0; ni < 4; ++ni)
        acc[mi][ni] = __builtin_amdgcn_mfma_f32_16x16x32_bf16(af[mi], bfr[ni], acc[mi][ni], 0, 0, 0);

    if (AF32 && ks + 1 < nk) writeA32(buf ^ 1);
    buf ^= 1;
  }

  if (EPI == 2) {
    short* Kb = (short*)Cout;
    short* Vt = (short*)Cout2;
    #pragma unroll
    for (int mi = 0; mi < 4; ++mi) {
      int row0 = mbase + wr + mi * 16 + (g << 2);     // = b*512 + key0
      int b = row0 >> 9, key0 = row0 & 511;
      #pragma unroll
      for (int ni = 0; ni < 4; ++ni) {
        int col = nbase + wc + ni * 16 + c15;
        if (col < 512) {
          int h = col >> 6, d = col & 63;
          size_t base = ((size_t)((b << 3) + h) << 15) + d;
          #pragma unroll
          for (int r = 0; r < 4; ++r)
            Kb[base + ((size_t)(key0 + r) << 6)] = sbf(acc[mi][ni][r]);
        } else {
          int cc = col - 512;
          int h = cc >> 6, d = cc & 63;
          size_t base = ((size_t)((b << 3) + h) << 15) + ((size_t)d << 9) + key0;
          bf4 o4;
          #pragma unroll
          for (int r = 0; r < 4; ++r) o4[r] = sbf(acc[mi][ni][r]);
          *(bf4*)&Vt[base] = o4;
        }
      }
    }
  } else {
    #pragma unroll
    for (int mi = 0; mi < 4; ++mi) {
      int row0 = mbase + wr + mi * 16 + (g << 2);
      #pragma unroll
      for (int ni = 0; ni < 4; ++ni) {
        int col = nbase + wc + ni * 16 + c15;
        #pragma unroll
        for (int r = 0; r < 4; ++r) {
          float v = acc[mi][ni][r];
          if (EPI == 1) {
            v += bias[col];
            ((float*)Cout)[(size_t)(row0 + r) * N + col] = v;
          } else {
            ((short*)Cout)[(size_t)(row0 + r) * N + col] = sbf(v);
          }
        }
      }
    }
  }
}

// ---------------- gemm256: 256x256 tile, 8 waves (Q-proj / out-proj, N=512) ----------------
// 1-D grid, N-fastest pairing: p -> (m = p>>1, n = p&1). The two blocks sharing an
// A-panel launch back-to-back so the 2nd A read hits L2/L3 hot (R17's 144MB FETCH
// showed scattered re-reads miss L3). Kernel body = R13-proven skeleton, unchanged.
template<int EPI, bool AF32>
__global__ __launch_bounds__(512, 2)
void gemm256(const void* __restrict__ Av, const short* __restrict__ Bt,
             void* __restrict__ Cout, void* __restrict__ Cout2,
             const float* __restrict__ bias, int M, int N, int K) {
  extern __shared__ short smem[];          // As: [2][8192], Bs: [2][8192]
  short* As = smem;
  short* Bs = smem + 16384;
  const short* A16 = (const short*)Av;
  const float* A32 = (const float*)Av;
  const int tid = threadIdx.x;
  const int w = tid >> 6, l = tid & 63, g = l >> 4, c15 = l & 15;
  const int mbase = (blockIdx.x >> 1) * 256, nbase = (blockIdx.x & 1) * 256;
  const int wrM = (w >> 2) * 128, wc = (w & 3) * 64;

  f32x4 acc[8][4];
  #pragma unroll
  for (int mi = 0; mi < 8; ++mi)
    #pragma unroll
    for (int ni = 0; ni < 4; ++ni) acc[mi][ni] = (f32x4){0.f, 0.f, 0.f, 0.f};

  int rowS[2], loS[2];
  #pragma unroll
  for (int p = 0; p < 2; ++p) {
    int pb = p * 8192 + tid * 16;
    rowS[p] = pb >> 6;
    loS[p] = ((pb & 63) ^ ((rowS[p] & 3) << 4)) >> 1;
  }

  const int ar = tid >> 1, ac0 = (tid & 1) * 16, acl = (tid & 1) * 2;
  short* wdst0 = &As[ar * 32 + 8 * ((acl + 0) ^ (ar & 3))];
  short* wdst1 = &As[ar * 32 + 8 * ((acl + 1) ^ (ar & 3))];

  auto stageB = [&](int ks, int b) {
    #pragma unroll
    for (int p = 0; p < 2; ++p) {
      const short* gb = Bt + (size_t)(nbase + rowS[p]) * K + (ks << 5) + loS[p];
      __builtin_amdgcn_global_load_lds((const AS1 void*)gb,
          (AS3 void*)(Bs + b * 8192 + p * 4096 + tid * 8), 16, 0, 0);
    }
  };
  auto stageA16 = [&](int ks, int b) {
    #pragma unroll
    for (int p = 0; p < 2; ++p) {
      const short* ga = A16 + (size_t)(mbase + rowS[p]) * K + (ks << 5) + loS[p];
      __builtin_amdgcn_global_load_lds((const AS1 void*)ga,
          (AS3 void*)(As + b * 8192 + p * 4096 + tid * 8), 16, 0, 0);
    }
  };

  const int nk = K >> 5;
  fvec4 a0, a1, a2, a3;
  auto loadA32 = [&](int ks) {
    const float* p = A32 + (size_t)(mbase + ar) * K + (ks << 5) + ac0;
    a0 = *(const fvec4*)(p);
    a1 = *(const fvec4*)(p + 4);
    a2 = *(const fvec4*)(p + 8);
    a3 = *(const fvec4*)(p + 12);
  };
  auto writeA32 = [&](int b) {
    uvec4 w0, w1;
    w0[0] = pk2(a0[0], a0[1]); w0[1] = pk2(a0[2], a0[3]);
    w0[2] = pk2(a1[0], a1[1]); w0[3] = pk2(a1[2], a1[3]);
    w1[0] = pk2(a2[0], a2[1]); w1[1] = pk2(a2[2], a2[3]);
    w1[2] = pk2(a3[0], a3[1]); w1[3] = pk2(a3[2], a3[3]);
    *(uvec4*)(wdst0 + b * 8192) = w0;
    *(uvec4*)(wdst1 + b * 8192) = w1;
  };

  if (AF32) { loadA32(0); writeA32(0); }
  else      { stageA16(0, 0); }
  stageB(0, 0);

  int buf = 0;
  for (int ks = 0; ks < nk; ++ks) {
    asm volatile("s_waitcnt vmcnt(0) lgkmcnt(0)\ns_barrier" ::: "memory");
    if (ks + 1 < nk) {
      if (AF32) loadA32(ks + 1);
      else      stageA16(ks + 1, buf ^ 1);
      stageB(ks + 1, buf ^ 1);
    }

    bf8 bfr[4];
    #pragma unroll
    for (int ni = 0; ni < 4; ++ni) {
      int row = wc + ni * 16 + c15;
      bfr[ni] = *(const bf8*)&Bs[buf * 8192 + (row << 5) + ((g << 3) ^ ((row & 3) << 3))];
    }
    #pragma unroll
    for (int mi = 0; mi < 8; ++mi) {
      int row = wrM + mi * 16 + c15;
      bf8 af = *(const bf8*)&As[buf * 8192 + (row << 5) + ((g << 3) ^ ((row & 3) << 3))];
      #pragma unroll
      for (int ni = 0; ni < 4; ++ni)
        acc[mi][ni] = __builtin_amdgcn_mfma_f32_16x16x32_bf16(af, bfr[ni], acc[mi][ni], 0, 0, 0);
    }

    if (AF32 && ks + 1 < nk) writeA32(buf ^ 1);
    buf ^= 1;
  }

  #pragma unroll
  for (int mi = 0; mi < 8; ++mi) {
    int row0 = mbase + wrM + mi * 16 + (g << 2);
    #pragma unroll
    for (int ni = 0; ni < 4; ++ni) {
      int col = nbase + wc + ni * 16 + c15;
      #pragma unroll
      for (int r = 0; r < 4; ++r) {
        float v = acc[mi][ni][r];
        if (EPI == 1) {
          v += bias[col];
          ((float*)Cout)[(size_t)(row0 + r) * N + col] = v;
        } else {
          ((short*)Cout)[(size_t)(row0 + r) * N + col] = sbf(v);
        }
      }
    }
  }
}

// ---------------- fused attention v9 (R14-exact, proven 49.3us / FETCH 20.5MB) ----------------
// LESSONS PINNED (do not revisit):
//   (R6, R15) ANY deeper prefetch (counted vmcnt ring), with or without XCD swizzle,
//             triples KV L2-fill (FETCH 20->60+MB) and costs +18-160us. 1-deep is load-bearing.
//   (R8, R10) Any reg cap below the full 128 allocation spills catastrophically. Keep (512,4).
__global__ __launch_bounds__(512, 4)
void attn_fwd(const short* __restrict__ Q, const short* __restrict__ Kb,
              const short* __restrict__ Vt, short* __restrict__ O) {
  extern __shared__ short smem[];   // [2][64][64] K + [2][64][64] V = 16384 shorts (32 KB)

  const int p = blockIdx.x;
  const int v = (p & 7) * 128 + (p >> 3);    // XCD-chunked virtual id
  const int bh = v >> 4, qx = v & 15;
  const int tid = threadIdx.x;
  const int w = tid >> 6, l = tid & 63, q = l & 31, h2 = l >> 5;
  const int bb = bh >> 3, h = bh & 7;
  const size_t orow0 = (size_t)bb * 4096 + qx * 256;
  const size_t kvbase = (size_t)bh << 15;    // per-head 512*64 shorts

  bf8 qf[4];
  #pragma unroll
  for (int ds = 0; ds < 4; ++ds)
    qf[ds] = *(const bf8*)(Q + (orow0 + w * 32 + q) * 512 + h * 64 + ds * 16 + 8 * h2);

  const int srow = tid >> 3;
  const int soff = (tid & 7) * 16;
  const int slo  = (soff ^ ((srow & 7) << 4)) >> 1;
  const short* srcK0 = Kb + kvbase + ((size_t)srow << 6) + slo;
  const short* srcV0 = Vt + kvbase + ((size_t)srow << 9) + slo;

#define STAGE(t) do { \
    __builtin_amdgcn_global_load_lds((const AS1 void*)(srcK0 + ((size_t)(t) << 12)), \
        (AS3 void*)(smem + ((t) & 1) * 4096 + tid * 8), 16, 0, 0); \
    __builtin_amdgcn_global_load_lds((const AS1 void*)(srcV0 + ((t) << 6)), \
        (AS3 void*)(smem + 8192 + ((t) & 1) * 4096 + tid * 8), 16, 0, 0); } while (0)

  f32x16 o[2];
  #pragma unroll
  for (int db = 0; db < 2; ++db)
    #pragma unroll
    for (int r = 0; r < 16; ++r) o[db][r] = 0.f;
  float ls0 = 0.f, ls1 = 0.f, ls2 = 0.f, ls3 = 0.f;

  STAGE(0);

  #pragma unroll 2
  for (int t = 0; t < 8; ++t) {
    asm volatile("s_waitcnt vmcnt(0)\ns_barrier" ::: "memory");
    if (t < 7) STAGE(t + 1);
    const short* Kt  = smem + (t & 1) * 4096;
    const short* Vtl = smem + 8192 + (t & 1) * 4096;

    f32x16 s[2];
    __builtin_amdgcn_s_setprio(1);
    #pragma unroll
    for (int kb = 0; kb < 2; ++kb) {
      #pragma unroll
      for (int r = 0; r < 16; ++r) s[kb][r] = 0.f;
      #pragma unroll
      for (int ds = 0; ds < 4; ++ds) {
        bf8 kf = *(const bf8*)&Kt[((kb * 32 + q) << 6) +
                                  ((ds * 16 + 8 * h2) ^ ((q & 7) << 3))];
        s[kb] = __builtin_amdgcn_mfma_f32_32x32x16_bf16(kf, qf[ds], s[kb], 0, 0, 0);
      }
    }
    __builtin_amdgcn_s_setprio(0);

    #pragma unroll
    for (int kb = 0; kb < 2; ++kb)
      #pragma unroll
      for (int r = 0; r < 16; r += 4) {
        float p0 = EXP2(s[kb][r]);
        float p1 = EXP2(s[kb][r + 1]);
        float p2 = EXP2(s[kb][r + 2]);
        float p3 = EXP2(s[kb][r + 3]);
        s[kb][r] = p0; s[kb][r + 1] = p1; s[kb][r + 2] = p2; s[kb][r + 3] = p3;
        ls0 += p0; ls1 += p1; ls2 += p2; ls3 += p3;
      }

    #pragma unroll
    for (int ks = 0; ks < 4; ++ks) {
      const int kb = ks >> 1, rb = (ks & 1) * 8;
      unsigned X = pk2(s[kb][rb + 0], s[kb][rb + 1]);
      unsigned Y = pk2(s[kb][rb + 2], s[kb][rb + 3]);
      unsigned Z = pk2(s[kb][rb + 4], s[kb][rb + 5]);
      unsigned W = pk2(s[kb][rb + 6], s[kb][rb + 7]);
      asm volatile("v_permlane32_swap_b32 %0, %1" : "+v"(X), "+v"(Z));
      asm volatile("v_permlane32_swap_b32 %0, %1" : "+v"(Y), "+v"(W));
      union { unsigned u[4]; bf8 b; } pf;
      pf.u[0] = X; pf.u[1] = Y; pf.u[2] = Z; pf.u[3] = W;
      __builtin_amdgcn_s_setprio(1);
      #pragma unroll
      for (int db = 0; db < 2; ++db) {
        bf8 vf = *(const bf8*)&Vtl[((db * 32 + q) << 6) +
                                   ((ks * 16 + 8 * h2) ^ ((q & 7) << 3))];
        o[db] = __builtin_amdgcn_mfma_f32_32x32x16_bf16(vf, pf.b, o[db], 0, 0, 0);
      }
      __builtin_amdgcn_s_setprio(0);
    }
  }
#undef STAGE

  float lsum = (ls0 + ls1) + (ls2 + ls3);
  float tot = lsum + __shfl_xor(lsum, 32);
  float rs = 1.0f / tot;
  short* Orow = O + (orow0 + w * 32 + q) * 512 + h * 64;
  #pragma unroll
  for (int db = 0; db < 2; ++db)
    #pragma unroll
    for (int rq = 0; rq < 4; ++rq) {
      int r = rq * 4;
      uvec2 u;
      u[0] = pk2(o[db][r] * rs,     o[db][r + 1] * rs);
      u[1] = pk2(o[db][r + 2] * rs, o[db][r + 3] * rs);
      *(uvec2*)&Orow[db * 32 + rq * 8 + h2 * 4] = u;
    }
}

// ---------------- launcher ----------------
extern "C" void kernel_launch(void* const* d_in, const int* in_sizes, int n_in,
                              void* d_out, int out_size, void* d_ws, size_t ws_size,
                              hipStream_t stream) {
  const float* x   = (const float*)d_in[0];
  const float* ctx = (const float*)d_in[1];
  const float* wq  = (const float*)d_in[2];
  const float* wk  = (const float*)d_in[3];
  const float* wv  = (const float*)d_in[4];
  const float* wo  = (const float*)d_in[5];
  const float* bo  = (const float*)d_in[6];
  float* out = (float*)d_out;

  char* ws = (char*)d_ws;
  short* wqT  = (short*)(ws + 39845888);   // [512][512] (pre-scaled by 0.125*log2e)
  short* wkvT = (short*)(ws + 40370176);   // [1024][768] (wk^T stacked on wv^T)
  short* woT  = (short*)(ws + 41943040);   // [512][512]
  short* Qb   = (short*)(ws + 42467328);   // [32768][512]
  short* Kbf  = (short*)(ws + 76021760);   // [64 bh][512 key][64 d]
  short* Vtf  = (short*)(ws + 80216064);   // [64 bh][64 d][512 key]
  short* Ab   = (short*)(ws + 84410368);   // [32768][512]

  (void)hipFuncSetAttribute((const void*)attn_fwd,
                            hipFuncAttributeMaxDynamicSharedMemorySize, 32768);
  (void)hipFuncSetAttribute((const void*)gemm256<0, true>,
                            hipFuncAttributeMaxDynamicSharedMemorySize, 65536);
  (void)hipFuncSetAttribute((const void*)gemm256<1, false>,
                            hipFuncAttributeMaxDynamicSharedMemorySize, 65536);

  const float QSCALE = 0.18033688011f;     // 0.125 * log2(e)

  prep_weights<<<320, 256, 0, stream>>>(wq, wk, wv, wo, wqT, wkvT, woT, QSCALE);

  // Q = x(fp32) @ (wq * QSCALE) : M=32768, N=512 — 256^2 tiles, N-fastest pairing
  gemm256<0, true><<<dim3(256), 512, 65536, stream>>>(x, wqT, Qb, nullptr, nullptr, 32768, 512, 512);
  // [K|V] = ctx(fp32) @ [wk|wv]: M=4096, N=1024 — 128^2 tiles, 256 blocks, XCD-grouped
  gemm128<2, true><<<dim3(256), 256, 0, stream>>>(ctx, wkvT, Kbf, Vtf, nullptr, 4096, 1024, 768);
  // attention (R14-exact)
  attn_fwd<<<dim3(1024), 512, 32768, stream>>>(Qb, Kbf, Vtf, Ab);
  // out = A(bf16) @ wo + b : fp32 output — 256^2 tiles, N-fastest pairing
  gemm256<1, false><<<dim3(256), 512, 65536, stream>>>(Ab, woT, out, nullptr, bo, 32768, 512, 512);
}

// Round 20
// 137.653 us; speedup vs baseline: 1.0383x; 1.0383x over previous
//
#include <hip/hip_runtime.h>
#include <hip/hip_bf16.h>
#include <stdint.h>

typedef __attribute__((ext_vector_type(4)))  float  f32x4;
typedef __attribute__((ext_vector_type(16))) float  f32x16;
typedef __attribute__((ext_vector_type(8)))  short  bf8;   // 8 bf16 bit patterns (4 VGPRs)
typedef __attribute__((ext_vector_type(4)))  short  bf4;
typedef __attribute__((ext_vector_type(4)))  float  fvec4;
typedef __attribute__((ext_vector_type(4)))  unsigned uvec4;
typedef __attribute__((ext_vector_type(2)))  unsigned uvec2;

#define AS1 __attribute__((address_space(1)))
#define AS3 __attribute__((address_space(3)))

#if __has_builtin(__builtin_amdgcn_exp2f)
#define EXP2(x) __builtin_amdgcn_exp2f(x)
#else
#define EXP2(x) exp2f(x)
#endif

__device__ __forceinline__ short sbf(float f) {
  __hip_bfloat16 h = __float2bfloat16(f);
  return *reinterpret_cast<short*>(&h);
}

// packed f32x2 -> bf16x2 in one HW instruction (low = lo, high = hi)
__device__ __forceinline__ unsigned pk2(float lo, float hi) {
  unsigned r;
  asm("v_cvt_pk_bf16_f32 %0, %1, %2" : "=v"(r) : "v"(lo), "v"(hi));
  return r;
}

// ---------------- all 4 weight transposes in ONE launch ----------------
__device__ __forceinline__ void tr_tile(const float* __restrict__ src,
                                        short* __restrict__ dst, int K,
                                        float scale, int kx, int ny) {
  __shared__ short t[64][65];
  const int k0 = kx * 64, n0 = ny * 64;
  const int tx = threadIdx.x & 15, ty = threadIdx.x >> 4;   // 16x16
  #pragma unroll
  for (int i = 0; i < 4; ++i) {
    int k = ty + i * 16;
    fvec4 v = *(const fvec4*)(src + (size_t)(k0 + k) * 512 + n0 + tx * 4);
    t[tx * 4 + 0][k] = sbf(v[0] * scale);
    t[tx * 4 + 1][k] = sbf(v[1] * scale);
    t[tx * 4 + 2][k] = sbf(v[2] * scale);
    t[tx * 4 + 3][k] = sbf(v[3] * scale);
  }
  __syncthreads();
  #pragma unroll
  for (int i = 0; i < 4; ++i) {
    int n = ty + i * 16;
    bf4 o = *(bf4*)&t[n][tx * 4];
    *(bf4*)(dst + (size_t)(n0 + n) * K + k0 + tx * 4) = o;
  }
}

__global__ __launch_bounds__(256)
void prep_weights(const float* __restrict__ wq, const float* __restrict__ wk,
                  const float* __restrict__ wv, const float* __restrict__ wo,
                  short* __restrict__ wqT, short* __restrict__ wkvT,
                  short* __restrict__ woT, float qscale) {
  int bx = blockIdx.x;
  if (bx < 64)        tr_tile(wq, wqT, 512, qscale, bx & 7, bx >> 3);
  else if (bx < 160)  { int l = bx - 64;  tr_tile(wk, wkvT,            768, 1.0f, l % 12, l / 12); }
  else if (bx < 256)  { int l = bx - 160; tr_tile(wv, wkvT + 512*768,  768, 1.0f, l % 12, l / 12); }
  else                { int l = bx - 256; tr_tile(wo, woT, 512, 1.0f, l & 7, l >> 3); }
}

// ---------------- gemm128: 128x128 tile, 4 waves (proven R12/R16, KV-proj) ----------------
// 1-D grid with XCD grouping (256 blocks, bijective). 2-phase dbuf, vmcnt(0)/K-step.
// AF32: A fp32 reg-staged via v_cvt_pk + swizzled ds_write (same LDS image).
// EPI: 0 bf16 C; 1 f32 C + bias; 2 KV split (K->[bh][key][64]; V->[bh][d][512]).
template<int EPI, bool AF32>
__global__ __launch_bounds__(256, 3)
void gemm128(const void* __restrict__ Av, const short* __restrict__ Bt,
             void* __restrict__ Cout, void* __restrict__ Cout2,
             const float* __restrict__ bias, int M, int N, int K) {
  __shared__ short As[2][4096];
  __shared__ short Bs[2][4096];
  const short* A16 = (const short*)Av;
  const float* A32 = (const float*)Av;
  const int tid = threadIdx.x;
  const int w = tid >> 6, l = tid & 63, g = l >> 4, c15 = l & 15;
  const int nbN = N >> 7;
  const int vv = (blockIdx.x & 7) * (gridDim.x >> 3) + (blockIdx.x >> 3);
  const int mbase = (vv / nbN) * 128, nbase = (vv % nbN) * 128;
  const int wr = (w >> 1) << 6, wc = (w & 1) << 6;

  f32x4 acc[4][4];
  #pragma unroll
  for (int mi = 0; mi < 4; ++mi)
    #pragma unroll
    for (int ni = 0; ni < 4; ++ni) acc[mi][ni] = (f32x4){0.f, 0.f, 0.f, 0.f};

  int rowS[2], loS[2];
  #pragma unroll
  for (int p = 0; p < 2; ++p) {
    int pb = p * 4096 + tid * 16;
    rowS[p] = pb >> 6;
    loS[p] = ((pb & 63) ^ ((rowS[p] & 3) << 4)) >> 1;
  }

  const int ar = tid >> 1, ac0 = (tid & 1) * 16, acl = (tid & 1) * 2;
  short* wdst0 = &As[0][ar * 32 + 8 * ((acl + 0) ^ (ar & 3))];
  short* wdst1 = &As[0][ar * 32 + 8 * ((acl + 1) ^ (ar & 3))];

  auto stageB = [&](int ks, int b) {
    #pragma unroll
    for (int p = 0; p < 2; ++p) {
      const short* gb = Bt + (size_t)(nbase + rowS[p]) * K + (ks << 5) + loS[p];
      __builtin_amdgcn_global_load_lds((const AS1 void*)gb,
          (AS3 void*)(&Bs[b][p * 2048 + w * 512]), 16, 0, 0);
    }
  };
  auto stageA16 = [&](int ks, int b) {
    #pragma unroll
    for (int p = 0; p < 2; ++p) {
      const short* ga = A16 + (size_t)(mbase + rowS[p]) * K + (ks << 5) + loS[p];
      __builtin_amdgcn_global_load_lds((const AS1 void*)ga,
          (AS3 void*)(&As[b][p * 2048 + w * 512]), 16, 0, 0);
    }
  };

  const int nk = K >> 5;
  fvec4 a0, a1, a2, a3;
  auto loadA32 = [&](int ks) {
    const float* p = A32 + (size_t)(mbase + ar) * K + (ks << 5) + ac0;
    a0 = *(const fvec4*)(p);
    a1 = *(const fvec4*)(p + 4);
    a2 = *(const fvec4*)(p + 8);
    a3 = *(const fvec4*)(p + 12);
  };
  auto writeA32 = [&](int b) {
    uvec4 w0, w1;
    w0[0] = pk2(a0[0], a0[1]); w0[1] = pk2(a0[2], a0[3]);
    w0[2] = pk2(a1[0], a1[1]); w0[3] = pk2(a1[2], a1[3]);
    w1[0] = pk2(a2[0], a2[1]); w1[1] = pk2(a2[2], a2[3]);
    w1[2] = pk2(a3[0], a3[1]); w1[3] = pk2(a3[2], a3[3]);
    *(uvec4*)(wdst0 + b * 4096) = w0;
    *(uvec4*)(wdst1 + b * 4096) = w1;
  };

  if (AF32) { loadA32(0); writeA32(0); }
  else      { stageA16(0, 0); }
  stageB(0, 0);

  int buf = 0;
  for (int ks = 0; ks < nk; ++ks) {
    asm volatile("s_waitcnt vmcnt(0) lgkmcnt(0)\ns_barrier" ::: "memory");
    if (ks + 1 < nk) {
      if (AF32) loadA32(ks + 1);
      else      stageA16(ks + 1, buf ^ 1);
      stageB(ks + 1, buf ^ 1);
    }

    bf8 af[4], bfr[4];
    #pragma unroll
    for (int mi = 0; mi < 4; ++mi) {
      int row = wr + mi * 16 + c15;
      af[mi] = *(const bf8*)&As[buf][(row << 5) + ((g << 3) ^ ((row & 3) << 3))];
    }
    #pragma unroll
    for (int ni = 0; ni < 4; ++ni) {
      int row = wc + ni * 16 + c15;
      bfr[ni] = *(const bf8*)&Bs[buf][(row << 5) + ((g << 3) ^ ((row & 3) << 3))];
    }
    #pragma unroll
    for (int mi = 0; mi < 4; ++mi)
      #pragma unroll
      for (int ni = 0; ni < 4; ++ni)
        acc[mi][ni] = __builtin_amdgcn_mfma_f32_16x16x32_bf16(af[mi], bfr[ni], acc[mi][ni], 0, 0, 0);

    if (AF32 && ks + 1 < nk) writeA32(buf ^ 1);
    buf ^= 1;
  }

  if (EPI == 2) {
    short* Kb = (short*)Cout;
    short* Vt = (short*)Cout2;
    #pragma unroll
    for (int mi = 0; mi < 4; ++mi) {
      int row0 = mbase + wr + mi * 16 + (g << 2);     // = b*512 + key0
      int b = row0 >> 9, key0 = row0 & 511;
      #pragma unroll
      for (int ni = 0; ni < 4; ++ni) {
        int col = nbase + wc + ni * 16 + c15;
        if (col < 512) {
          int h = col >> 6, d = col & 63;
          size_t base = ((size_t)((b << 3) + h) << 15) + d;
          #pragma unroll
          for (int r = 0; r < 4; ++r)
            Kb[base + ((size_t)(key0 + r) << 6)] = sbf(acc[mi][ni][r]);
        } else {
          int cc = col - 512;
          int h = cc >> 6, d = cc & 63;
          size_t base = ((size_t)((b << 3) + h) << 15) + ((size_t)d << 9) + key0;
          bf4 o4;
          #pragma unroll
          for (int r = 0; r < 4; ++r) o4[r] = sbf(acc[mi][ni][r]);
          *(bf4*)&Vt[base] = o4;
        }
      }
    }
  } else {
    #pragma unroll
    for (int mi = 0; mi < 4; ++mi) {
      int row0 = mbase + wr + mi * 16 + (g << 2);
      #pragma unroll
      for (int ni = 0; ni < 4; ++ni) {
        int col = nbase + wc + ni * 16 + c15;
        #pragma unroll
        for (int r = 0; r < 4; ++r) {
          float v = acc[mi][ni][r];
          if (EPI == 1) {
            v += bias[col];
            ((float*)Cout)[(size_t)(row0 + r) * N + col] = v;
          } else {
            ((short*)Cout)[(size_t)(row0 + r) * N + col] = sbf(v);
          }
        }
      }
    }
  }
}

// ---------------- gemm256: 256x256 tile, 8 waves (Q-proj / out-proj) ----------------
// 2-D grid (128,2) — R14/R16-proven. (R18's 1-D N-fastest pairing regressed +5us; reverted.)
template<int EPI, bool AF32>
__global__ __launch_bounds__(512, 2)
void gemm256(const void* __restrict__ Av, const short* __restrict__ Bt,
             void* __restrict__ Cout, void* __restrict__ Cout2,
             const float* __restrict__ bias, int M, int N, int K) {
  extern __shared__ short smem[];          // As: [2][8192], Bs: [2][8192]
  short* As = smem;
  short* Bs = smem + 16384;
  const short* A16 = (const short*)Av;
  const float* A32 = (const float*)Av;
  const int tid = threadIdx.x;
  const int w = tid >> 6, l = tid & 63, g = l >> 4, c15 = l & 15;
  const int mbase = blockIdx.x * 256, nbase = blockIdx.y * 256;
  const int wrM = (w >> 2) * 128, wc = (w & 3) * 64;

  f32x4 acc[8][4];
  #pragma unroll
  for (int mi = 0; mi < 8; ++mi)
    #pragma unroll
    for (int ni = 0; ni < 4; ++ni) acc[mi][ni] = (f32x4){0.f, 0.f, 0.f, 0.f};

  int rowS[2], loS[2];
  #pragma unroll
  for (int p = 0; p < 2; ++p) {
    int pb = p * 8192 + tid * 16;
    rowS[p] = pb >> 6;
    loS[p] = ((pb & 63) ^ ((rowS[p] & 3) << 4)) >> 1;
  }

  const int ar = tid >> 1, ac0 = (tid & 1) * 16, acl = (tid & 1) * 2;
  short* wdst0 = &As[ar * 32 + 8 * ((acl + 0) ^ (ar & 3))];
  short* wdst1 = &As[ar * 32 + 8 * ((acl + 1) ^ (ar & 3))];

  auto stageB = [&](int ks, int b) {
    #pragma unroll
    for (int p = 0; p < 2; ++p) {
      const short* gb = Bt + (size_t)(nbase + rowS[p]) * K + (ks << 5) + loS[p];
      __builtin_amdgcn_global_load_lds((const AS1 void*)gb,
          (AS3 void*)(Bs + b * 8192 + p * 4096 + tid * 8), 16, 0, 0);
    }
  };
  auto stageA16 = [&](int ks, int b) {
    #pragma unroll
    for (int p = 0; p < 2; ++p) {
      const short* ga = A16 + (size_t)(mbase + rowS[p]) * K + (ks << 5) + loS[p];
      __builtin_amdgcn_global_load_lds((const AS1 void*)ga,
          (AS3 void*)(As + b * 8192 + p * 4096 + tid * 8), 16, 0, 0);
    }
  };

  const int nk = K >> 5;
  fvec4 a0, a1, a2, a3;
  auto loadA32 = [&](int ks) {
    const float* p = A32 + (size_t)(mbase + ar) * K + (ks << 5) + ac0;
    a0 = *(const fvec4*)(p);
    a1 = *(const fvec4*)(p + 4);
    a2 = *(const fvec4*)(p + 8);
    a3 = *(const fvec4*)(p + 12);
  };
  auto writeA32 = [&](int b) {
    uvec4 w0, w1;
    w0[0] = pk2(a0[0], a0[1]); w0[1] = pk2(a0[2], a0[3]);
    w0[2] = pk2(a1[0], a1[1]); w0[3] = pk2(a1[2], a1[3]);
    w1[0] = pk2(a2[0], a2[1]); w1[1] = pk2(a2[2], a2[3]);
    w1[2] = pk2(a3[0], a3[1]); w1[3] = pk2(a3[2], a3[3]);
    *(uvec4*)(wdst0 + b * 8192) = w0;
    *(uvec4*)(wdst1 + b * 8192) = w1;
  };

  if (AF32) { loadA32(0); writeA32(0); }
  else      { stageA16(0, 0); }
  stageB(0, 0);

  int buf = 0;
  for (int ks = 0; ks < nk; ++ks) {
    asm volatile("s_waitcnt vmcnt(0) lgkmcnt(0)\ns_barrier" ::: "memory");
    if (ks + 1 < nk) {
      if (AF32) loadA32(ks + 1);
      else      stageA16(ks + 1, buf ^ 1);
      stageB(ks + 1, buf ^ 1);
    }

    bf8 bfr[4];
    #pragma unroll
    for (int ni = 0; ni < 4; ++ni) {
      int row = wc + ni * 16 + c15;
      bfr[ni] = *(const bf8*)&Bs[buf * 8192 + (row << 5) + ((g << 3) ^ ((row & 3) << 3))];
    }
    #pragma unroll
    for (int mi = 0; mi < 8; ++mi) {
      int row = wrM + mi * 16 + c15;
      bf8 af = *(const bf8*)&As[buf * 8192 + (row << 5) + ((g << 3) ^ ((row & 3) << 3))];
      #pragma unroll
      for (int ni = 0; ni < 4; ++ni)
        acc[mi][ni] = __builtin_amdgcn_mfma_f32_16x16x32_bf16(af, bfr[ni], acc[mi][ni], 0, 0, 0);
    }

    if (AF32 && ks + 1 < nk) writeA32(buf ^ 1);
    buf ^= 1;
  }

  #pragma unroll
  for (int mi = 0; mi < 8; ++mi) {
    int row0 = mbase + wrM + mi * 16 + (g << 2);
    #pragma unroll
    for (int ni = 0; ni < 4; ++ni) {
      int col = nbase + wc + ni * 16 + c15;
      #pragma unroll
      for (int r = 0; r < 4; ++r) {
        float v = acc[mi][ni][r];
        if (EPI == 1) {
          v += bias[col];
          ((float*)Cout)[(size_t)(row0 + r) * N + col] = v;
        } else {
          ((short*)Cout)[(size_t)(row0 + r) * N + col] = sbf(v);
        }
      }
    }
  }
}

// ---------------- fused attention v9 (R14/R16-exact, proven 49.3us / FETCH 20.5MB) ----------------
// LESSONS PINNED (do not revisit):
//   (R6, R15) ANY deeper prefetch (counted vmcnt ring), with or without XCD swizzle,
//             triples KV L2-fill (FETCH 20->60+MB) and costs +18-160us. 1-deep is load-bearing.
//   (R8, R10) Any reg cap below the full 128 allocation spills catastrophically. Keep (512,4).
__global__ __launch_bounds__(512, 4)
void attn_fwd(const short* __restrict__ Q, const short* __restrict__ Kb,
              const short* __restrict__ Vt, short* __restrict__ O) {
  extern __shared__ short smem[];   // [2][64][64] K + [2][64][64] V = 16384 shorts (32 KB)

  const int p = blockIdx.x;
  const int v = (p & 7) * 128 + (p >> 3);    // XCD-chunked virtual id
  const int bh = v >> 4, qx = v & 15;
  const int tid = threadIdx.x;
  const int w = tid >> 6, l = tid & 63, q = l & 31, h2 = l >> 5;
  const int bb = bh >> 3, h = bh & 7;
  const size_t orow0 = (size_t)bb * 4096 + qx * 256;
  const size_t kvbase = (size_t)bh << 15;    // per-head 512*64 shorts

  bf8 qf[4];
  #pragma unroll
  for (int ds = 0; ds < 4; ++ds)
    qf[ds] = *(const bf8*)(Q + (orow0 + w * 32 + q) * 512 + h * 64 + ds * 16 + 8 * h2);

  const int srow = tid >> 3;
  const int soff = (tid & 7) * 16;
  const int slo  = (soff ^ ((srow & 7) << 4)) >> 1;
  const short* srcK0 = Kb + kvbase + ((size_t)srow << 6) + slo;
  const short* srcV0 = Vt + kvbase + ((size_t)srow << 9) + slo;

#define STAGE(t) do { \
    __builtin_amdgcn_global_load_lds((const AS1 void*)(srcK0 + ((size_t)(t) << 12)), \
        (AS3 void*)(smem + ((t) & 1) * 4096 + tid * 8), 16, 0, 0); \
    __builtin_amdgcn_global_load_lds((const AS1 void*)(srcV0 + ((t) << 6)), \
        (AS3 void*)(smem + 8192 + ((t) & 1) * 4096 + tid * 8), 16, 0, 0); } while (0)

  f32x16 o[2];
  #pragma unroll
  for (int db = 0; db < 2; ++db)
    #pragma unroll
    for (int r = 0; r < 16; ++r) o[db][r] = 0.f;
  float ls0 = 0.f, ls1 = 0.f, ls2 = 0.f, ls3 = 0.f;

  STAGE(0);

  #pragma unroll 2
  for (int t = 0; t < 8; ++t) {
    asm volatile("s_waitcnt vmcnt(0)\ns_barrier" ::: "memory");
    if (t < 7) STAGE(t + 1);
    const short* Kt  = smem + (t & 1) * 4096;
    const short* Vtl = smem + 8192 + (t & 1) * 4096;

    f32x16 s[2];
    __builtin_amdgcn_s_setprio(1);
    #pragma unroll
    for (int kb = 0; kb < 2; ++kb) {
      #pragma unroll
      for (int r = 0; r < 16; ++r) s[kb][r] = 0.f;
      #pragma unroll
      for (int ds = 0; ds < 4; ++ds) {
        bf8 kf = *(const bf8*)&Kt[((kb * 32 + q) << 6) +
                                  ((ds * 16 + 8 * h2) ^ ((q & 7) << 3))];
        s[kb] = __builtin_amdgcn_mfma_f32_32x32x16_bf16(kf, qf[ds], s[kb], 0, 0, 0);
      }
    }
    __builtin_amdgcn_s_setprio(0);

    #pragma unroll
    for (int kb = 0; kb < 2; ++kb)
      #pragma unroll
      for (int r = 0; r < 16; r += 4) {
        float p0 = EXP2(s[kb][r]);
        float p1 = EXP2(s[kb][r + 1]);
        float p2 = EXP2(s[kb][r + 2]);
        float p3 = EXP2(s[kb][r + 3]);
        s[kb][r] = p0; s[kb][r + 1] = p1; s[kb][r + 2] = p2; s[kb][r + 3] = p3;
        ls0 += p0; ls1 += p1; ls2 += p2; ls3 += p3;
      }

    #pragma unroll
    for (int ks = 0; ks < 4; ++ks) {
      const int kb = ks >> 1, rb = (ks & 1) * 8;
      unsigned X = pk2(s[kb][rb + 0], s[kb][rb + 1]);
      unsigned Y = pk2(s[kb][rb + 2], s[kb][rb + 3]);
      unsigned Z = pk2(s[kb][rb + 4], s[kb][rb + 5]);
      unsigned W = pk2(s[kb][rb + 6], s[kb][rb + 7]);
      asm volatile("v_permlane32_swap_b32 %0, %1" : "+v"(X), "+v"(Z));
      asm volatile("v_permlane32_swap_b32 %0, %1" : "+v"(Y), "+v"(W));
      union { unsigned u[4]; bf8 b; } pf;
      pf.u[0] = X; pf.u[1] = Y; pf.u[2] = Z; pf.u[3] = W;
      __builtin_amdgcn_s_setprio(1);
      #pragma unroll
      for (int db = 0; db < 2; ++db) {
        bf8 vf = *(const bf8*)&Vtl[((db * 32 + q) << 6) +
                                   ((ks * 16 + 8 * h2) ^ ((q & 7) << 3))];
        o[db] = __builtin_amdgcn_mfma_f32_32x32x16_bf16(vf, pf.b, o[db], 0, 0, 0);
      }
      __builtin_amdgcn_s_setprio(0);
    }
  }
#undef STAGE

  float lsum = (ls0 + ls1) + (ls2 + ls3);
  float tot = lsum + __shfl_xor(lsum, 32);
  float rs = 1.0f / tot;
  short* Orow = O + (orow0 + w * 32 + q) * 512 + h * 64;
  #pragma unroll
  for (int db = 0; db < 2; ++db)
    #pragma unroll
    for (int rq = 0; rq < 4; ++rq) {
      int r = rq * 4;
      uvec2 u;
      u[0] = pk2(o[db][r] * rs,     o[db][r + 1] * rs);
      u[1] = pk2(o[db][r + 2] * rs, o[db][r + 3] * rs);
      *(uvec2*)&Orow[db * 32 + rq * 8 + h2 * 4] = u;
    }
}

// ---------------- launcher ----------------
extern "C" void kernel_launch(void* const* d_in, const int* in_sizes, int n_in,
                              void* d_out, int out_size, void* d_ws, size_t ws_size,
                              hipStream_t stream) {
  const float* x   = (const float*)d_in[0];
  const float* ctx = (const float*)d_in[1];
  const float* wq  = (const float*)d_in[2];
  const float* wk  = (const float*)d_in[3];
  const float* wv  = (const float*)d_in[4];
  const float* wo  = (const float*)d_in[5];
  const float* bo  = (const float*)d_in[6];
  float* out = (float*)d_out;

  char* ws = (char*)d_ws;
  short* wqT  = (short*)(ws + 39845888);   // [512][512] (pre-scaled by 0.125*log2e)
  short* wkvT = (short*)(ws + 40370176);   // [1024][768] (wk^T stacked on wv^T)
  short* woT  = (short*)(ws + 41943040);   // [512][512]
  short* Qb   = (short*)(ws + 42467328);   // [32768][512]
  short* Kbf  = (short*)(ws + 76021760);   // [64 bh][512 key][64 d]
  short* Vtf  = (short*)(ws + 80216064);   // [64 bh][64 d][512 key]
  short* Ab   = (short*)(ws + 84410368);   // [32768][512]

  (void)hipFuncSetAttribute((const void*)attn_fwd,
                            hipFuncAttributeMaxDynamicSharedMemorySize, 32768);
  (void)hipFuncSetAttribute((const void*)gemm256<0, true>,
                            hipFuncAttributeMaxDynamicSharedMemorySize, 65536);
  (void)hipFuncSetAttribute((const void*)gemm256<1, false>,
                            hipFuncAttributeMaxDynamicSharedMemorySize, 65536);

  const float QSCALE = 0.18033688011f;     // 0.125 * log2(e)

  prep_weights<<<320, 256, 0, stream>>>(wq, wk, wv, wo, wqT, wkvT, woT, QSCALE);

  // Q = x(fp32) @ (wq * QSCALE) : M=32768, N=512 — 256^2 tiles, 256 blocks (1/CU)
  gemm256<0, true><<<dim3(128, 2), 512, 65536, stream>>>(x, wqT, Qb, nullptr, nullptr, 32768, 512, 512);
  // [K|V] = ctx(fp32) @ [wk|wv]: M=4096, N=1024 — 128^2 tiles, 256 blocks, XCD-grouped
  gemm128<2, true><<<dim3(256), 256, 0, stream>>>(ctx, wkvT, Kbf, Vtf, nullptr, 4096, 1024, 768);
  // attention (R14-exact)
  attn_fwd<<<dim3(1024), 512, 32768, stream>>>(Qb, Kbf, Vtf, Ab);
  // out = A(bf16) @ wo + b : fp32 output — 256^2 tiles
  gemm256<1, false><<<dim3(128, 2), 512, 65536, stream>>>(Ab, woT, out, nullptr, bo, 32768, 512, 512);
}